// Round 1
// baseline (740.740 us; speedup 1.0000x reference)
//
#include <hip/hip_runtime.h>

// MovementPrunedLinear: out[m][n] = sum_k x[m][k] * W[n][k] * mask(n/32, k/32) + bias[n]
// M=8192 (B*S), N=4096 (D_OUT), K=4096 (D_IN). Mask: scores[nb][kb] > logit(0.1).
// Strategy R1: m93-style 128x128x32 bf16 MFMA tile GEMM, fp32->bf16 convert during
// LDS staging (inputs are fp32; threshold is bf16-scale so bf16 MFMA is licensed).

#define BM 128
#define BN 128
#define BK 32
#define LDSS (BK + 8)   // +8 bf16 pad (16B = 4 banks) -> ds_read_b128 conflicts <= 2-way (free)

typedef __attribute__((ext_vector_type(8))) short bf16x8;   // 8 bf16 = 4 VGPRs (guide-verified type)
typedef __attribute__((ext_vector_type(4))) float f32x4;

__device__ __forceinline__ unsigned short f2bf(float f) {
    // round-to-nearest-even fp32 -> bf16 (inputs are finite; no NaN path needed)
    union { float f; unsigned u; } v; v.f = f;
    return (unsigned short)((v.u + 0x7FFFu + ((v.u >> 16) & 1u)) >> 16);
}

__global__ __launch_bounds__(256, 2)
void mpl_gemm(const float* __restrict__ X,      // [M,K]
              const float* __restrict__ W,      // [N,K]
              const float* __restrict__ bias,   // [N]
              const float* __restrict__ scores, // [N/32, K/32]
              float* __restrict__ out,          // [M,N]
              int M, int N, int K)
{
    __shared__ unsigned short sA[BM * LDSS];
    __shared__ unsigned short sB[BN * LDSS];

    const int tid  = threadIdx.x;
    const int m0   = blockIdx.y * BM;
    const int n0   = blockIdx.x * BN;
    const int wave = tid >> 6;
    const int lane = tid & 63;
    const int wm   = (wave & 1) * 64;    // wave's m offset in tile (2x2 wave grid, 64x64 each)
    const int wn   = (wave >> 1) * 64;

    const int kblocks = K >> 5;
    const float THRESH = -2.1972245773362196f;   // logit(0.1)

    f32x4 acc[4][4];
#pragma unroll
    for (int i = 0; i < 4; i++)
#pragma unroll
        for (int j = 0; j < 4; j++)
            acc[i][j] = (f32x4){0.f, 0.f, 0.f, 0.f};

    // Staging decomposition: tile = 128 rows x 8 float4; 1024 float4s over 256 threads, 4 each.
    int srow[4], sc4[4], snb[4];
#pragma unroll
    for (int i = 0; i < 4; i++) {
        int f = tid + 256 * i;
        srow[i] = f >> 3;
        sc4[i]  = f & 7;
        snb[i]  = (n0 + srow[i]) >> 5;   // scores row for B staging
    }

    for (int k0 = 0; k0 < K; k0 += BK) {
        const int kb = k0 >> 5;

        // ---- stage A (x): fp32 -> bf16 ----
#pragma unroll
        for (int i = 0; i < 4; i++) {
            const float4 v = *(const float4*)(X + (long)(m0 + srow[i]) * K + k0 + sc4[i] * 4);
            unsigned short* dst = &sA[srow[i] * LDSS + sc4[i] * 4];
            ushort4 p;
            p.x = f2bf(v.x); p.y = f2bf(v.y); p.z = f2bf(v.z); p.w = f2bf(v.w);
            *(ushort4*)dst = p;
        }
        // ---- stage B (W) with block mask: fp32 -> bf16 ----
#pragma unroll
        for (int i = 0; i < 4; i++) {
            const float msk = (scores[snb[i] * kblocks + kb] > THRESH) ? 1.0f : 0.0f;
            const float4 v = *(const float4*)(W + (long)(n0 + srow[i]) * K + k0 + sc4[i] * 4);
            unsigned short* dst = &sB[srow[i] * LDSS + sc4[i] * 4];
            ushort4 p;
            p.x = f2bf(v.x * msk); p.y = f2bf(v.y * msk);
            p.z = f2bf(v.z * msk); p.w = f2bf(v.w * msk);
            *(ushort4*)dst = p;
        }
        __syncthreads();

        // ---- fragments: A[m=lane&15][k=quad*8+j], B[n=lane&15][k=quad*8+j] (B^T form) ----
        const int fr = lane & 15;
        const int kq = (lane >> 4) * 8;
        bf16x8 af[4], bfr[4];
#pragma unroll
        for (int mi = 0; mi < 4; mi++)
            af[mi] = *(const bf16x8*)&sA[(wm + mi * 16 + fr) * LDSS + kq];
#pragma unroll
        for (int ni = 0; ni < 4; ni++)
            bfr[ni] = *(const bf16x8*)&sB[(wn + ni * 16 + fr) * LDSS + kq];

#pragma unroll
        for (int mi = 0; mi < 4; mi++)
#pragma unroll
            for (int ni = 0; ni < 4; ni++)
                acc[mi][ni] = __builtin_amdgcn_mfma_f32_16x16x32_bf16(
                    af[mi], bfr[ni], acc[mi][ni], 0, 0, 0);

        __syncthreads();
    }

    // ---- epilogue: C/D layout col=lane&15 (n), row=(lane>>4)*4+reg (m) ----
    const int cn = lane & 15;
    const int rq = (lane >> 4) * 4;
#pragma unroll
    for (int ni = 0; ni < 4; ni++) {
        const int n = n0 + wn + ni * 16 + cn;
        const float b = bias[n];
#pragma unroll
        for (int mi = 0; mi < 4; mi++) {
#pragma unroll
            for (int r = 0; r < 4; r++) {
                const int m = m0 + wm + mi * 16 + rq + r;
                out[(long)m * N + n] = acc[mi][ni][r] + b;
            }
        }
    }
}

extern "C" void kernel_launch(void* const* d_in, const int* in_sizes, int n_in,
                              void* d_out, int out_size, void* d_ws, size_t ws_size,
                              hipStream_t stream) {
    const float* X      = (const float*)d_in[0];
    const float* W      = (const float*)d_in[1];
    const float* bias   = (const float*)d_in[2];
    const float* scores = (const float*)d_in[3];
    float* out          = (float*)d_out;

    const int N = in_sizes[2];            // D_OUT = bias size = 4096
    const int K = in_sizes[1] / N;        // D_IN = 4096
    const int M = in_sizes[0] / K;        // B*S = 8192

    dim3 grid(N / BN, M / BM);            // (32, 64)
    mpl_gemm<<<grid, dim3(256), 0, stream>>>(X, W, bias, scores, out, M, N, K);
}

// Round 2
// 546.786 us; speedup vs baseline: 1.3547x; 1.3547x over previous
//
#include <hip/hip_runtime.h>

// MovementPrunedLinear R2: pre-pass (fp32->bf16 X, masked bf16 W, packed mask bits)
// + m97-style GEMM (global_load_lds width-16 staging, 128x128x32 bf16 MFMA)
// + per-wave block-sparsity skip (~50% of (nb,kb) blocks masked).

#define BM 128
#define BN 128
#define BK 32

typedef __attribute__((ext_vector_type(8))) short bf16x8;
typedef __attribute__((ext_vector_type(4))) float f32x4;

__device__ __forceinline__ unsigned short f2bf(float f) {
    union { float f; unsigned u; } v; v.f = f;
    return (unsigned short)((v.u + 0x7FFFu + ((v.u >> 16) & 1u)) >> 16);
}

#define THRESH (-2.1972245773362196f)   // logit(0.1)

// ---------------- pre-pass kernels ----------------

__global__ void conv_x(const float* __restrict__ X, unsigned short* __restrict__ Xb) {
    const long i = ((long)blockIdx.x * 256 + threadIdx.x) * 8;
    const float4 a = *(const float4*)(X + i);
    const float4 b = *(const float4*)(X + i + 4);
    ushort4 p, q;
    p.x = f2bf(a.x); p.y = f2bf(a.y); p.z = f2bf(a.z); p.w = f2bf(a.w);
    q.x = f2bf(b.x); q.y = f2bf(b.y); q.z = f2bf(b.z); q.w = f2bf(b.w);
    *(ushort4*)(Xb + i) = p;
    *(ushort4*)(Xb + i + 4) = q;
}

__global__ void conv_w(const float* __restrict__ W, const float* __restrict__ scores,
                       unsigned short* __restrict__ Wb, int K, int KB) {
    const long i = ((long)blockIdx.x * 256 + threadIdx.x) * 8;
    const int n = (int)(i / K);
    const int k = (int)(i % K);          // 8 elems never cross a 32-boundary (8 | 32)
    const float msk = (scores[(n >> 5) * KB + (k >> 5)] > THRESH) ? 1.0f : 0.0f;
    const float4 a = *(const float4*)(W + i);
    const float4 b = *(const float4*)(W + i + 4);
    ushort4 p, q;
    p.x = f2bf(a.x * msk); p.y = f2bf(a.y * msk); p.z = f2bf(a.z * msk); p.w = f2bf(a.w * msk);
    q.x = f2bf(b.x * msk); q.y = f2bf(b.y * msk); q.z = f2bf(b.z * msk); q.w = f2bf(b.w * msk);
    *(ushort4*)(Wb + i) = p;
    *(ushort4*)(Wb + i + 4) = q;
}

// KB == 128 exactly: pack scores[nb][0..127] > TH into 2 u64 per nb.
__global__ void pack_mask(const float* __restrict__ scores, unsigned long long* __restrict__ mb,
                          int KB) {
    const int nb = blockIdx.x;
    const int l  = threadIdx.x;   // 64 threads
    const unsigned long long b0 = __ballot(scores[nb * KB + l] > THRESH);
    const unsigned long long b1 = __ballot(scores[nb * KB + 64 + l] > THRESH);
    if (l == 0) { mb[nb * 2] = b0; mb[nb * 2 + 1] = b1; }
}

// ---------------- main GEMM ----------------

__device__ __forceinline__ unsigned long long rfl64(unsigned long long v) {
    unsigned lo = __builtin_amdgcn_readfirstlane((unsigned)v);
    unsigned hi = __builtin_amdgcn_readfirstlane((unsigned)(v >> 32));
    return ((unsigned long long)hi << 32) | lo;
}

#define GLL16(g, l) __builtin_amdgcn_global_load_lds( \
    (const __attribute__((address_space(1))) void*)(g), \
    (__attribute__((address_space(3))) void*)(l), 16, 0, 0)

__global__ __launch_bounds__(256)
void mpl_main(const unsigned short* __restrict__ Xb,   // [M,K] bf16
              const unsigned short* __restrict__ Wb,   // [N,K] bf16, pre-masked
              const float* __restrict__ bias,
              const unsigned long long* __restrict__ mb, // [N/32][2]
              float* __restrict__ out, int M, int N, int K)
{
    __shared__ unsigned short sA[BM * BK];   // 8 KB, unpadded (global_load_lds constraint)
    __shared__ unsigned short sB[BN * BK];   // 8 KB

    const int tid  = threadIdx.x;
    const int lane = tid & 63;
    const int wave = tid >> 6;
    const int m0   = blockIdx.y * BM;
    const int n0   = blockIdx.x * BN;
    const int wm   = (wave & 1) * 64;
    const int wn   = (wave >> 1) * 64;
    const int KB   = K >> 5;                 // 128

    // mask bits: this wave's two n-blocks + block-wide "any" bits (all uniform)
    const int nbb  = n0 >> 5;
    const int mynb = nbb + (wn >> 5);
    const unsigned long long w0lo = rfl64(mb[mynb * 2]),       w0hi = rfl64(mb[mynb * 2 + 1]);
    const unsigned long long w1lo = rfl64(mb[(mynb + 1) * 2]), w1hi = rfl64(mb[(mynb + 1) * 2 + 1]);
    const unsigned long long anylo = rfl64(mb[nbb*2] | mb[nbb*2+2] | mb[nbb*2+4] | mb[nbb*2+6]);
    const unsigned long long anyhi = rfl64(mb[nbb*2+1] | mb[nbb*2+3] | mb[nbb*2+5] | mb[nbb*2+7]);

    f32x4 acc[4][4];
#pragma unroll
    for (int i = 0; i < 4; i++)
#pragma unroll
        for (int j = 0; j < 4; j++)
            acc[i][j] = (f32x4){0.f, 0.f, 0.f, 0.f};

    // Staging: tile row = 64 B. Instr i covers rows i*64..i*64+63; thread's row = tid>>2 (+64),
    // col byte = (tid&3)*16. LDS dest base (wave-uniform) = wave*1024 + i*4096 bytes.
    const int srow = tid >> 2;
    const int scol = (tid & 3) * 16;
    const char* gA0 = (const char*)Xb + (long)(m0 + srow) * K * 2 + scol;
    const char* gA1 = (const char*)Xb + (long)(m0 + srow + 64) * K * 2 + scol;
    const char* gB0 = (const char*)Wb + (long)(n0 + srow) * K * 2 + scol;
    const char* gB1 = (const char*)Wb + (long)(n0 + srow + 64) * K * 2 + scol;
    char* sAc = (char*)sA;
    char* sBc = (char*)sB;
    char* ldsA0 = sAc + wave * 1024;
    char* ldsA1 = sAc + wave * 1024 + 4096;
    char* ldsB0 = sBc + wave * 1024;
    char* ldsB1 = sBc + wave * 1024 + 4096;

    const int fr = lane & 15;
    const int kq = (lane >> 4) * 8;

    for (int kb = 0; kb < KB; kb++) {
        const bool any = (kb < 64) ? ((anylo >> kb) & 1ULL) : ((anyhi >> (kb - 64)) & 1ULL);
        if (!any) continue;   // uniform across block: all 4 n-blocks masked at this kb

        const long ko = (long)kb * 64;   // 32 bf16 = 64 bytes per row
        GLL16(gA0 + ko, ldsA0);
        GLL16(gA1 + ko, ldsA1);
        GLL16(gB0 + ko, ldsB0);
        GLL16(gB1 + ko, ldsB1);
        __syncthreads();                 // compiler drains vmcnt before s_barrier

        bf16x8 af[4];
#pragma unroll
        for (int mi = 0; mi < 4; mi++)
            af[mi] = *(const bf16x8*)&sA[(wm + mi * 16 + fr) * BK + kq];

        const bool b0 = (kb < 64) ? ((w0lo >> kb) & 1ULL) : ((w0hi >> (kb - 64)) & 1ULL);
        const bool b1 = (kb < 64) ? ((w1lo >> kb) & 1ULL) : ((w1hi >> (kb - 64)) & 1ULL);

        if (b0) {
            bf16x8 bf0 = *(const bf16x8*)&sB[(wn + 0 * 16 + fr) * BK + kq];
            bf16x8 bf1 = *(const bf16x8*)&sB[(wn + 1 * 16 + fr) * BK + kq];
#pragma unroll
            for (int mi = 0; mi < 4; mi++) {
                acc[mi][0] = __builtin_amdgcn_mfma_f32_16x16x32_bf16(af[mi], bf0, acc[mi][0], 0, 0, 0);
                acc[mi][1] = __builtin_amdgcn_mfma_f32_16x16x32_bf16(af[mi], bf1, acc[mi][1], 0, 0, 0);
            }
        }
        if (b1) {
            bf16x8 bf2 = *(const bf16x8*)&sB[(wn + 2 * 16 + fr) * BK + kq];
            bf16x8 bf3 = *(const bf16x8*)&sB[(wn + 3 * 16 + fr) * BK + kq];
#pragma unroll
            for (int mi = 0; mi < 4; mi++) {
                acc[mi][2] = __builtin_amdgcn_mfma_f32_16x16x32_bf16(af[mi], bf2, acc[mi][2], 0, 0, 0);
                acc[mi][3] = __builtin_amdgcn_mfma_f32_16x16x32_bf16(af[mi], bf3, acc[mi][3], 0, 0, 0);
            }
        }
        __syncthreads();
    }

    // epilogue: C/D layout col=lane&15 (n), row=(lane>>4)*4+reg (m)
    const int cn = lane & 15;
    const int rq = (lane >> 4) * 4;
#pragma unroll
    for (int ni = 0; ni < 4; ni++) {
        const int n = n0 + wn + ni * 16 + cn;
        const float b = bias[n];
#pragma unroll
        for (int mi = 0; mi < 4; mi++) {
#pragma unroll
            for (int r = 0; r < 4; r++) {
                const int m = m0 + wm + mi * 16 + rq + r;
                out[(long)m * N + n] = acc[mi][ni][r] + b;
            }
        }
    }
}

// ---------------- fallback (R1 kernel, used if ws too small) ----------------

#define LDSS (BK + 8)
__global__ __launch_bounds__(256, 2)
void mpl_gemm_fb(const float* __restrict__ X, const float* __restrict__ W,
                 const float* __restrict__ bias, const float* __restrict__ scores,
                 float* __restrict__ out, int M, int N, int K)
{
    __shared__ unsigned short sA[BM * LDSS];
    __shared__ unsigned short sB[BN * LDSS];
    const int tid = threadIdx.x;
    const int m0 = blockIdx.y * BM, n0 = blockIdx.x * BN;
    const int wave = tid >> 6, lane = tid & 63;
    const int wm = (wave & 1) * 64, wn = (wave >> 1) * 64;
    const int kblocks = K >> 5;
    f32x4 acc[4][4];
#pragma unroll
    for (int i = 0; i < 4; i++)
#pragma unroll
        for (int j = 0; j < 4; j++) acc[i][j] = (f32x4){0.f,0.f,0.f,0.f};
    int srow[4], sc4[4], snb[4];
#pragma unroll
    for (int i = 0; i < 4; i++) {
        int f = tid + 256 * i;
        srow[i] = f >> 3; sc4[i] = f & 7; snb[i] = (n0 + srow[i]) >> 5;
    }
    for (int k0 = 0; k0 < K; k0 += BK) {
        const int kb = k0 >> 5;
#pragma unroll
        for (int i = 0; i < 4; i++) {
            const float4 v = *(const float4*)(X + (long)(m0 + srow[i]) * K + k0 + sc4[i] * 4);
            ushort4 p; p.x = f2bf(v.x); p.y = f2bf(v.y); p.z = f2bf(v.z); p.w = f2bf(v.w);
            *(ushort4*)&sA[srow[i] * LDSS + sc4[i] * 4] = p;
        }
#pragma unroll
        for (int i = 0; i < 4; i++) {
            const float msk = (scores[snb[i] * kblocks + kb] > THRESH) ? 1.0f : 0.0f;
            const float4 v = *(const float4*)(W + (long)(n0 + srow[i]) * K + k0 + sc4[i] * 4);
            ushort4 p; p.x = f2bf(v.x*msk); p.y = f2bf(v.y*msk); p.z = f2bf(v.z*msk); p.w = f2bf(v.w*msk);
            *(ushort4*)&sB[srow[i] * LDSS + sc4[i] * 4] = p;
        }
        __syncthreads();
        const int fr = lane & 15, kq = (lane >> 4) * 8;
        bf16x8 af[4], bfr[4];
#pragma unroll
        for (int mi = 0; mi < 4; mi++) af[mi] = *(const bf16x8*)&sA[(wm + mi*16 + fr) * LDSS + kq];
#pragma unroll
        for (int ni = 0; ni < 4; ni++) bfr[ni] = *(const bf16x8*)&sB[(wn + ni*16 + fr) * LDSS + kq];
#pragma unroll
        for (int mi = 0; mi < 4; mi++)
#pragma unroll
            for (int ni = 0; ni < 4; ni++)
                acc[mi][ni] = __builtin_amdgcn_mfma_f32_16x16x32_bf16(af[mi], bfr[ni], acc[mi][ni], 0,0,0);
        __syncthreads();
    }
    const int cn = lane & 15, rq = (lane >> 4) * 4;
#pragma unroll
    for (int ni = 0; ni < 4; ni++) {
        const int n = n0 + wn + ni * 16 + cn;
        const float b = bias[n];
#pragma unroll
        for (int mi = 0; mi < 4; mi++)
#pragma unroll
            for (int r = 0; r < 4; r++)
                out[(long)(m0 + wm + mi*16 + rq + r) * N + n] = acc[mi][ni][r] + b;
    }
}

extern "C" void kernel_launch(void* const* d_in, const int* in_sizes, int n_in,
                              void* d_out, int out_size, void* d_ws, size_t ws_size,
                              hipStream_t stream) {
    const float* X      = (const float*)d_in[0];
    const float* W      = (const float*)d_in[1];
    const float* bias   = (const float*)d_in[2];
    const float* scores = (const float*)d_in[3];
    float* out          = (float*)d_out;

    const int N = in_sizes[2];            // 4096
    const int K = in_sizes[1] / N;        // 4096
    const int M = in_sizes[0] / K;        // 8192
    const int KB = K >> 5;                // 128
    const int NB = N >> 5;                // 128

    const size_t mk2 = (size_t)M * K * 2;
    const size_t nk2 = (size_t)N * K * 2;
    const size_t need = mk2 + nk2 + (size_t)NB * 16;

    if (ws_size >= need && KB == 128 && (M % 128) == 0 && (N % 128) == 0 && (K % 2048) == 0) {
        unsigned short* Xb = (unsigned short*)d_ws;
        unsigned short* Wb = (unsigned short*)((char*)d_ws + mk2);
        unsigned long long* mbits = (unsigned long long*)((char*)d_ws + mk2 + nk2);

        conv_x<<<(int)((long)M * K / 2048), 256, 0, stream>>>(X, Xb);
        conv_w<<<(int)((long)N * K / 2048), 256, 0, stream>>>(W, scores, Wb, K, KB);
        pack_mask<<<NB, 64, 0, stream>>>(scores, mbits, KB);

        dim3 grid(N / BN, M / BM);
        mpl_main<<<grid, dim3(256), 0, stream>>>(Xb, Wb, bias, mbits, out, M, N, K);
    } else {
        dim3 grid(N / BN, M / BM);
        mpl_gemm_fb<<<grid, dim3(256), 0, stream>>>(X, W, bias, scores, out, M, N, K);
    }
}

// Round 3
// 477.550 us; speedup vs baseline: 1.5511x; 1.1450x over previous
//
#include <hip/hip_runtime.h>

// MovementPrunedLinear R3: merged prepass (bf16 X, masked bf16 W, packed mask)
// + BK=64 m97-style GEMM (global_load_lds w16, XOR-swizzled LDS, 128x128 tile)
// + per-nb B-staging skip and per-(nb,kb) MFMA skip.

#define BM 128
#define BN 128
#define BK 64

typedef __attribute__((ext_vector_type(8))) short bf16x8;
typedef __attribute__((ext_vector_type(4))) float f32x4;

__device__ __forceinline__ unsigned short f2bf(float f) {
    union { float f; unsigned u; } v; v.f = f;
    return (unsigned short)((v.u + 0x7FFFu + ((v.u >> 16) & 1u)) >> 16);
}

#define THRESH (-2.1972245773362196f)   // logit(0.1)

// ---------------- merged pre-pass ----------------
// blocks [0,M): convert X row b. blocks [M,M+N): convert+mask W row b-M.
// blocks [M+N, M+N+NB/4): pack mask bits, 4 nb per block (one per wave).
__global__ void prep(const float* __restrict__ X, const float* __restrict__ W,
                     const float* __restrict__ scores,
                     unsigned short* __restrict__ Xb, unsigned short* __restrict__ Wb,
                     unsigned long long* __restrict__ mbits,
                     int M, int N, int K) {
    const int b   = blockIdx.x;
    const int tid = threadIdx.x;
    const int KBlk = K >> 5;

    if (b < M + N) {
        const float* src;
        unsigned short* dst;
        const bool isW = (b >= M);
        const int n = isW ? (b - M) : 0;
        if (isW) { src = W + (long)n * K; dst = Wb + (long)n * K; }
        else     { src = X + (long)b * K; dst = Xb + (long)b * K; }
        const float* srow = isW ? scores + (long)(n >> 5) * KBlk : nullptr;

        for (int k = tid * 16; k < K; k += 4096) {
            const float msk = isW ? ((srow[k >> 5] > THRESH) ? 1.0f : 0.0f) : 1.0f;
            const float4 a = *(const float4*)(src + k);
            const float4 c = *(const float4*)(src + k + 4);
            const float4 e = *(const float4*)(src + k + 8);
            const float4 g = *(const float4*)(src + k + 12);
            ushort4 p, q, r, s;
            p.x = f2bf(a.x * msk); p.y = f2bf(a.y * msk); p.z = f2bf(a.z * msk); p.w = f2bf(a.w * msk);
            q.x = f2bf(c.x * msk); q.y = f2bf(c.y * msk); q.z = f2bf(c.z * msk); q.w = f2bf(c.w * msk);
            r.x = f2bf(e.x * msk); r.y = f2bf(e.y * msk); r.z = f2bf(e.z * msk); r.w = f2bf(e.w * msk);
            s.x = f2bf(g.x * msk); s.y = f2bf(g.y * msk); s.z = f2bf(g.z * msk); s.w = f2bf(g.w * msk);
            *(ushort4*)(dst + k)      = p;
            *(ushort4*)(dst + k + 4)  = q;
            *(ushort4*)(dst + k + 8)  = r;
            *(ushort4*)(dst + k + 12) = s;
        }
    } else {
        // mask pack: requires KBlk == 128 (guarded in launcher)
        const int nb = (b - (M + N)) * 4 + (tid >> 6);
        const int l  = tid & 63;
        const unsigned long long b0 = __ballot(scores[(long)nb * KBlk + l] > THRESH);
        const unsigned long long b1 = __ballot(scores[(long)nb * KBlk + 64 + l] > THRESH);
        if (l == 0) { mbits[nb * 2] = b0; mbits[nb * 2 + 1] = b1; }
    }
}

// ---------------- main GEMM ----------------

__device__ __forceinline__ unsigned long long rfl64(unsigned long long v) {
    unsigned lo = __builtin_amdgcn_readfirstlane((unsigned)v);
    unsigned hi = __builtin_amdgcn_readfirstlane((unsigned)(v >> 32));
    return ((unsigned long long)hi << 32) | lo;
}

#define GLL16(g, l) __builtin_amdgcn_global_load_lds( \
    (const __attribute__((address_space(1))) void*)(g), \
    (__attribute__((address_space(3))) void*)(l), 16, 0, 0)

__global__ __launch_bounds__(256)
void mpl_main(const unsigned short* __restrict__ Xb,   // [M,K] bf16
              const unsigned short* __restrict__ Wb,   // [N,K] bf16 pre-masked
              const float* __restrict__ bias,
              const unsigned long long* __restrict__ mb, // [N/32][2]
              float* __restrict__ out, int M, int N, int K)
{
    // Row = BK bf16 = 128 B = 8 chunks of 16 B. LDS slot (r, c') holds global
    // chunk c'^(r&7) (XOR swizzle via permuted global fetch; GLL dest is fixed).
    __shared__ unsigned short sA[BM * BK];   // 16 KB
    __shared__ unsigned short sB[BN * BK];   // 16 KB

    const int tid  = threadIdx.x;
    const int lane = tid & 63;
    const int wave = tid >> 6;
    const int m0   = blockIdx.y * BM;
    const int n0   = blockIdx.x * BN;
    const int wm   = (wave & 1) * 64;
    const int wn   = (wave >> 1) * 64;
    const long K2  = (long)K * 2;

    // per-nb mask words (scalarized)
    const int nbb = n0 >> 5;
    unsigned long long mlo[4], mhi[4];
#pragma unroll
    for (int i = 0; i < 4; i++) {
        mlo[i] = rfl64(mb[(nbb + i) * 2]);
        mhi[i] = rfl64(mb[(nbb + i) * 2 + 1]);
    }

    f32x4 acc[4][4];
#pragma unroll
    for (int i = 0; i < 4; i++)
#pragma unroll
        for (int j = 0; j < 4; j++)
            acc[i][j] = (f32x4){0.f, 0.f, 0.f, 0.f};

    // staging geometry: lane covers row (32i + tid>>3), swizzled chunk (tid&7)^((tid>>3)&7)
    const int r8   = tid >> 3;                               // 0..31
    const int cswz = ((tid & 7) ^ ((tid >> 3) & 7)) * 16;    // byte offset in row
    const char* gA = (const char*)Xb + (long)(m0 + r8) * K2 + cswz;
    const char* gB = (const char*)Wb + (long)(n0 + r8) * K2 + cswz;
    char* sAc = (char*)sA;
    char* sBc = (char*)sB;
    const int ldso = wave * 1024;

    // fragment geometry
    const int fr   = lane & 15;
    const int cxor = lane & 7;
    const int kqc  = lane >> 4;          // 0..3
    const int rowA = wm + fr;            // + mi*16
    const int rowB = wn + fr;            // + ni*16

    int kb2 = 0;
    for (int half = 0; half < 2; ++half) {
        const unsigned long long w0 = half ? mhi[0] : mlo[0];
        const unsigned long long w1 = half ? mhi[1] : mlo[1];
        const unsigned long long w2 = half ? mhi[2] : mlo[2];
        const unsigned long long w3 = half ? mhi[3] : mlo[3];
        for (int q = 0; q < 32; ++q, ++kb2) {
            const unsigned p0 = (unsigned)(w0 >> (2 * q)) & 3;
            const unsigned p1 = (unsigned)(w1 >> (2 * q)) & 3;
            const unsigned p2 = (unsigned)(w2 >> (2 * q)) & 3;
            const unsigned p3 = (unsigned)(w3 >> (2 * q)) & 3;
            if (!(p0 | p1 | p2 | p3)) continue;   // uniform across block

            const long ko = (long)kb2 * 128;
            // A staging: 4 instrs (rows 0..127)
#pragma unroll
            for (int i = 0; i < 4; i++)
                GLL16(gA + (long)i * 32 * K2 + ko, sAc + i * 4096 + ldso);
            // B staging: instr i == nb i; skip fully-masked pairs
            if (p0) GLL16(gB + 0L * 32 * K2 + ko, sBc + 0 * 4096 + ldso);
            if (p1) GLL16(gB + 1L * 32 * K2 + ko, sBc + 1 * 4096 + ldso);
            if (p2) GLL16(gB + 2L * 32 * K2 + ko, sBc + 2 * 4096 + ldso);
            if (p3) GLL16(gB + 3L * 32 * K2 + ko, sBc + 3 * 4096 + ldso);
            __syncthreads();

            const unsigned plo = (wave >> 1) ? p2 : p0;   // this wave's nb for ni 0,1
            const unsigned phi = (wave >> 1) ? p3 : p1;   // ni 2,3

#pragma unroll
            for (int kbl = 0; kbl < 2; ++kbl) {
                if (!(((plo | phi) >> kbl) & 1)) continue;
                const int boff = ((kqc | (kbl << 2)) ^ cxor) * 16;

                bf16x8 af[4];
#pragma unroll
                for (int mi = 0; mi < 4; mi++)
                    af[mi] = *(const bf16x8*)(sAc + (rowA + mi * 16) * 128 + boff);

                if ((plo >> kbl) & 1) {
                    const bf16x8 bf0 = *(const bf16x8*)(sBc + (rowB + 0)  * 128 + boff);
                    const bf16x8 bf1 = *(const bf16x8*)(sBc + (rowB + 16) * 128 + boff);
#pragma unroll
                    for (int mi = 0; mi < 4; mi++) {
                        acc[mi][0] = __builtin_amdgcn_mfma_f32_16x16x32_bf16(af[mi], bf0, acc[mi][0], 0, 0, 0);
                        acc[mi][1] = __builtin_amdgcn_mfma_f32_16x16x32_bf16(af[mi], bf1, acc[mi][1], 0, 0, 0);
                    }
                }
                if ((phi >> kbl) & 1) {
                    const bf16x8 bf2 = *(const bf16x8*)(sBc + (rowB + 32) * 128 + boff);
                    const bf16x8 bf3 = *(const bf16x8*)(sBc + (rowB + 48) * 128 + boff);
#pragma unroll
                    for (int mi = 0; mi < 4; mi++) {
                        acc[mi][2] = __builtin_amdgcn_mfma_f32_16x16x32_bf16(af[mi], bf2, acc[mi][2], 0, 0, 0);
                        acc[mi][3] = __builtin_amdgcn_mfma_f32_16x16x32_bf16(af[mi], bf3, acc[mi][3], 0, 0, 0);
                    }
                }
            }
            __syncthreads();
        }
    }

    // epilogue: C/D col=lane&15 (n), row=(lane>>4)*4+reg (m)
    const int cn = lane & 15;
    const int rq = (lane >> 4) * 4;
#pragma unroll
    for (int ni = 0; ni < 4; ni++) {
        const int n = n0 + wn + ni * 16 + cn;
        const float b = bias[n];
#pragma unroll
        for (int mi = 0; mi < 4; mi++) {
#pragma unroll
            for (int r = 0; r < 4; r++) {
                const int m = m0 + wm + mi * 16 + rq + r;
                out[(long)m * N + n] = acc[mi][ni][r] + b;
            }
        }
    }
}

// ---------------- fallback (R1 kernel) ----------------

#define FBK 32
#define LDSS (FBK + 8)
__global__ __launch_bounds__(256, 2)
void mpl_gemm_fb(const float* __restrict__ X, const float* __restrict__ W,
                 const float* __restrict__ bias, const float* __restrict__ scores,
                 float* __restrict__ out, int M, int N, int K)
{
    __shared__ unsigned short sA[BM * LDSS];
    __shared__ unsigned short sB[BN * LDSS];
    const int tid = threadIdx.x;
    const int m0 = blockIdx.y * BM, n0 = blockIdx.x * BN;
    const int wave = tid >> 6, lane = tid & 63;
    const int wm = (wave & 1) * 64, wn = (wave >> 1) * 64;
    const int kblocks = K >> 5;
    f32x4 acc[4][4];
#pragma unroll
    for (int i = 0; i < 4; i++)
#pragma unroll
        for (int j = 0; j < 4; j++) acc[i][j] = (f32x4){0.f,0.f,0.f,0.f};
    int srow[4], sc4[4], snb[4];
#pragma unroll
    for (int i = 0; i < 4; i++) {
        int f = tid + 256 * i;
        srow[i] = f >> 3; sc4[i] = f & 7; snb[i] = (n0 + srow[i]) >> 5;
    }
    for (int k0 = 0; k0 < K; k0 += FBK) {
        const int kb = k0 >> 5;
#pragma unroll
        for (int i = 0; i < 4; i++) {
            const float4 v = *(const float4*)(X + (long)(m0 + srow[i]) * K + k0 + sc4[i] * 4);
            ushort4 p; p.x = f2bf(v.x); p.y = f2bf(v.y); p.z = f2bf(v.z); p.w = f2bf(v.w);
            *(ushort4*)&sA[srow[i] * LDSS + sc4[i] * 4] = p;
        }
#pragma unroll
        for (int i = 0; i < 4; i++) {
            const float msk = (scores[snb[i] * kblocks + kb] > THRESH) ? 1.0f : 0.0f;
            const float4 v = *(const float4*)(W + (long)(n0 + srow[i]) * K + k0 + sc4[i] * 4);
            ushort4 p; p.x = f2bf(v.x*msk); p.y = f2bf(v.y*msk); p.z = f2bf(v.z*msk); p.w = f2bf(v.w*msk);
            *(ushort4*)&sB[srow[i] * LDSS + sc4[i] * 4] = p;
        }
        __syncthreads();
        const int fr = lane & 15, kq = (lane >> 4) * 8;
        bf16x8 af[4], bfr[4];
#pragma unroll
        for (int mi = 0; mi < 4; mi++) af[mi] = *(const bf16x8*)&sA[(wm + mi*16 + fr) * LDSS + kq];
#pragma unroll
        for (int ni = 0; ni < 4; ni++) bfr[ni] = *(const bf16x8*)&sB[(wn + ni*16 + fr) * LDSS + kq];
#pragma unroll
        for (int mi = 0; mi < 4; mi++)
#pragma unroll
            for (int ni = 0; ni < 4; ni++)
                acc[mi][ni] = __builtin_amdgcn_mfma_f32_16x16x32_bf16(af[mi], bfr[ni], acc[mi][ni], 0,0,0);
        __syncthreads();
    }
    const int cn = lane & 15, rq = (lane >> 4) * 4;
#pragma unroll
    for (int ni = 0; ni < 4; ni++) {
        const int n = n0 + wn + ni * 16 + cn;
        const float b = bias[n];
#pragma unroll
        for (int mi = 0; mi < 4; mi++)
#pragma unroll
            for (int r = 0; r < 4; r++)
                out[(long)(m0 + wm + mi*16 + rq + r) * N + n] = acc[mi][ni][r] + b;
    }
}

extern "C" void kernel_launch(void* const* d_in, const int* in_sizes, int n_in,
                              void* d_out, int out_size, void* d_ws, size_t ws_size,
                              hipStream_t stream) {
    const float* X      = (const float*)d_in[0];
    const float* W      = (const float*)d_in[1];
    const float* bias   = (const float*)d_in[2];
    const float* scores = (const float*)d_in[3];
    float* out          = (float*)d_out;

    const int N = in_sizes[2];            // 4096
    const int K = in_sizes[1] / N;        // 4096
    const int M = in_sizes[0] / K;        // 8192
    const int KB = K >> 5;                // 128
    const int NB = N >> 5;                // 128

    const size_t mk2 = (size_t)M * K * 2;
    const size_t nk2 = (size_t)N * K * 2;
    const size_t need = mk2 + nk2 + (size_t)NB * 16;

    if (ws_size >= need && KB == 128 && (M % 128) == 0 && (N % 128) == 0 &&
        (K % 4096) == 0 && (NB % 4) == 0) {
        unsigned short* Xb = (unsigned short*)d_ws;
        unsigned short* Wb = (unsigned short*)((char*)d_ws + mk2);
        unsigned long long* mbits = (unsigned long long*)((char*)d_ws + mk2 + nk2);

        prep<<<M + N + NB / 4, 256, 0, stream>>>(X, W, scores, Xb, Wb, mbits, M, N, K);

        dim3 grid(N / BN, M / BM);
        mpl_main<<<grid, dim3(256), 0, stream>>>(Xb, Wb, bias, mbits, out, M, N, K);
    } else {
        dim3 grid(N / BN, M / BM);
        mpl_gemm_fb<<<grid, dim3(256), 0, stream>>>(X, W, bias, scores, out, M, N, K);
    }
}